// Round 6
// baseline (74.554 us; speedup 1.0000x reference)
//
#include <hip/hip_runtime.h>

// SConv2d with MAJ3 tree reduction.
// x: (8, 27, 32, 32) f32, w: (27, 27, 3, 3) f32 -> out: (8, 27, 32, 32) f32.
// s-domain trick: (x+1)/2 ... 2r-1 cancels between tree levels; convert once
// at the leaves (s = (0.5*x)*w + 0.5, x prescaled) and once at the root.
//
// R5 = R4 structure (9-way (c3,c2) split, 4 px/thread b128+b64 reads,
// 864 blocks x 9 waves) WITHOUT the __launch_bounds__(576,7) VGPR cap that
// forced ~73 VGPRs and spilled the unrolled hot loop to scratch in R4.

#define HH 32
#define WW 32
#define CC 27
#define OCC 27

// majority gate on s-domain values: ab + ac + bc - 2abc (3 VALU ops)
__device__ __forceinline__ float maj3(float a, float b, float c) {
    float ab = a * b;
    float t  = fmaf(-2.0f, ab, a + b);   // a + b - 2ab
    return fmaf(c, t, ab);               // ab + c*(a+b-2ab)
}

// tile: 27 ch x 10 rows x stride 36 (38,880 B), prescaled 0.5, pad -0.5.
// part: 9 groups x 256 px (9,216 B). Total LDS 48,096 B.
__global__ __launch_bounds__(576) void sconv_maj_kernel(
    const float* __restrict__ x, const float* __restrict__ w, float* __restrict__ out)
{
    __shared__ float tile[270 * 36];
    __shared__ float part[9 * 256];

    const int b    = blockIdx.x;
    const int rg   = b & 3;            // 4 row-groups of 8 output rows
    const int rest = b >> 2;
    const int oc   = rest % OCC;       // blockIdx-derived -> scalar weights
    const int n    = rest / OCC;
    const int tid  = threadIdx.x;

    const float* __restrict__ xb = x + n * (CC * HH * WW);

    // ---- stage prescaled, padded tile (all 576 threads) ----
    {
        const int lane = tid & 31;     // column 0..31
        const int team = tid >> 5;     // 18 row-teams
        for (int R = team; R < 270; R += 18) {    // R = c*10 + tr
            const int c  = R / 10;
            const int tr = R - c * 10;
            const int ih = rg * 8 + tr - 1;
            float v = -0.5f;
            if ((unsigned)ih < 32u) v = 0.5f * xb[c * (HH * WW) + ih * WW + lane];
            tile[R * 36 + 1 + lane] = v;
        }
        for (int i = tid; i < 540; i += 576) {    // col 0 / col 33 borders
            const int R = i >> 1;
            tile[R * 36 + ((i & 1) ? 33 : 0)] = -0.5f;
        }
    }
    __syncthreads();

    // ---- partial trees: wave g = (c3*3+c2); thread = 4 px in one row ----
    const int g   = __builtin_amdgcn_readfirstlane(tid >> 6);  // 0..8, SGPR
    const int lt  = tid & 63;
    const int pr  = lt >> 3;           // pixel row 0..7
    const int ow0 = (lt & 7) << 2;     // columns ow0..ow0+3 (16B-aligned)

    {
        const float* __restrict__ wp = w + oc * 243 + g * 27;  // 3 channels
        float p3[4][3];
#pragma unroll
        for (int c1 = 0; c1 < 3; ++c1) {
            const int c = g * 3 + c1;                 // = c3*9 + c2*3 + c1
            const float* trow = &tile[(c * 10 + pr) * 36 + ow0];
            float rr[4][3];
#pragma unroll
            for (int kh = 0; kh < 3; ++kh) {
                // 6 consecutive taps for 4 px: b128 (16B-aligned) + b64
                const float4 u = *(const float4*)(trow + kh * 36);
                const float2 v = *(const float2*)(trow + kh * 36 + 4);
                const float w0 = wp[c1 * 9 + kh * 3 + 0];
                const float w1 = wp[c1 * 9 + kh * 3 + 1];
                const float w2 = wp[c1 * 9 + kh * 3 + 2];
                // leaf s = (x*w+1)/2 = (0.5x)*w + 0.5; level 1: kw
                rr[0][kh] = maj3(fmaf(u.x, w0, 0.5f), fmaf(u.y, w1, 0.5f), fmaf(u.z, w2, 0.5f));
                rr[1][kh] = maj3(fmaf(u.y, w0, 0.5f), fmaf(u.z, w1, 0.5f), fmaf(u.w, w2, 0.5f));
                rr[2][kh] = maj3(fmaf(u.z, w0, 0.5f), fmaf(u.w, w1, 0.5f), fmaf(v.x, w2, 0.5f));
                rr[3][kh] = maj3(fmaf(u.w, w0, 0.5f), fmaf(v.x, w1, 0.5f), fmaf(v.y, w2, 0.5f));
            }
#pragma unroll
            for (int p = 0; p < 4; ++p)               // level 2: kh
                p3[p][c1] = maj3(rr[p][0], rr[p][1], rr[p][2]);
        }
        float4 o;                                     // level 3: c1 (partial)
        o.x = maj3(p3[0][0], p3[0][1], p3[0][2]);
        o.y = maj3(p3[1][0], p3[1][1], p3[1][2]);
        o.z = maj3(p3[2][0], p3[2][1], p3[2][2]);
        o.w = maj3(p3[3][0], p3[3][1], p3[3][2]);
        *(float4*)(&part[g * 256 + pr * 32 + ow0]) = o;   // aligned b128 write
    }
    __syncthreads();

    // ---- combine: level 4 (c2), level 5 (c3), back-convert; 256 threads ----
    if (tid < 256) {
        const int px = tid;
        const float m0 = maj3(part[0 * 256 + px], part[1 * 256 + px], part[2 * 256 + px]);
        const float m1 = maj3(part[3 * 256 + px], part[4 * 256 + px], part[5 * 256 + px]);
        const float m2 = maj3(part[6 * 256 + px], part[7 * 256 + px], part[8 * 256 + px]);
        const float y  = fmaf(2.0f, maj3(m0, m1, m2), -1.0f);
        const int oh = rg * 8 + (px >> 5);
        const int ow = px & 31;
        out[(((n * OCC + oc) * HH) + oh) * WW + ow] = y;
    }
}

extern "C" void kernel_launch(void* const* d_in, const int* in_sizes, int n_in,
                              void* d_out, int out_size, void* d_ws, size_t ws_size,
                              hipStream_t stream) {
    const float* x = (const float*)d_in[0];
    const float* w = (const float*)d_in[1];
    float* out = (float*)d_out;
    // grid: 8 n * 27 oc * 4 row-groups = 864 blocks, 576 threads (9 waves)
    sconv_maj_kernel<<<dim3(8 * OCC * 4), dim3(576), 0, stream>>>(x, w, out);
}

// Round 7
// 61.392 us; speedup vs baseline: 1.2144x; 1.2144x over previous
//
#include <hip/hip_runtime.h>

// SConv2d with MAJ3 tree reduction.
// x: (8, 27, 32, 32) f32, w: (27, 27, 3, 3) f32 -> out: (8, 27, 32, 32) f32.
// s-domain trick: (x+1)/2 ... 2r-1 cancels between tree levels; convert once
// at the leaves (s = (0.5*x)*w + 0.5, x prescaled) and once at the root.
//
// R6 = exact replication of R3 (best measured: 61.8 us vs 72-75 for all
// neighbors; run-to-run noise established at ~±1 us by R1/R2 and R4/R5
// pairs). Structure: 3-way c3 split (wave = (oc_local, c3), combine over c3
// in phase 2 -> identical tree association), 2 px/thread aligned b64 reads
// (27 LDS reads/px), 448 blocks x 768 threads = 5.25 waves/SIMD, 72.6k
// staged tile rows. Neighbor cells in the (px/thread, split, oc-share)
// design space all regress: more TLP costs staging redundancy and vice
// versa under the 1024-thread block cap.

#define HH 32
#define WW 32
#define CC 27
#define OCC 27

// majority gate on s-domain values: ab + ac + bc - 2abc (3 VALU ops)
__device__ __forceinline__ float maj3(float a, float b, float c) {
    float ab = a * b;
    float t  = fmaf(-2.0f, ab, a + b);   // a + b - 2ab
    return fmaf(c, t, ab);               // ab + c*(a+b-2ab)
}

// tile: 27 ch x 6 rows x stride 36 floats (23.3 KB), prescaled 0.5, pad -0.5.
// partials: 4 oc x 128 px x 3 c3 floats (6 KB).
__global__ __launch_bounds__(768) void sconv_maj_kernel(
    const float* __restrict__ x, const float* __restrict__ w, float* __restrict__ out)
{
    __shared__ float smem[27 * 6 * 36 + 4 * 128 * 3];   // 29,472 B
    float* tile = smem;
    float* part = smem + 27 * 6 * 36;

    const int b    = blockIdx.x;
    const int rg   = b & 7;            // 8 row-groups of 4 output rows
    const int rest = b >> 3;
    const int ocg  = rest % 7;         // 7 groups of 4 oc (last has 3)
    const int n    = rest / 7;
    const int tid  = threadIdx.x;

    const float* __restrict__ xb = x + n * (CC * HH * WW);

    // ---- stage prescaled, padded tile (all 768 threads) ----
    {
        const int lane = tid & 31;     // column 0..31
        const int team = tid >> 5;     // 24 row-teams
        for (int R = team; R < 162; R += 24) {    // R = c*6 + tr
            const int c  = R / 6;
            const int tr = R - c * 6;
            const int ih = rg * 4 + tr - 1;
            float v = -0.5f;
            if ((unsigned)ih < 32u) v = 0.5f * xb[c * (HH * WW) + ih * WW + lane];
            tile[R * 36 + 1 + lane] = v;
        }
        for (int i = tid; i < 324; i += 768) {    // col 0 and col 33 borders
            const int R = i >> 1;
            tile[R * 36 + ((i & 1) ? 33 : 0)] = -0.5f;
        }
    }
    __syncthreads();

    // ---- partial trees: wave = (oc_local, c3); thread = 2 adjacent px ----
    const int wavei    = __builtin_amdgcn_readfirstlane(tid >> 6);  // 0..11, SGPR
    const int oc_local = wavei / 3;
    const int sub3     = wavei - oc_local * 3;       // c3 digit, scalar
    const int oc       = ocg * 4 + oc_local;         // scalar -> s_load weights
    const int lt  = tid & 63;
    const int pr  = lt >> 4;           // local pixel row 0..3
    const int ow0 = (lt & 15) << 1;    // even column pair ow0, ow0+1

    if (oc < OCC) {
        const float* __restrict__ wp = w + oc * 243 + sub3 * 81;  // 9 channels

        float l4a[3], l4b[3];
#pragma unroll
        for (int c2 = 0; c2 < 3; ++c2) {
            float l3a[3], l3b[3];
#pragma unroll
            for (int c1 = 0; c1 < 3; ++c1) {
                const int c  = sub3 * 9 + c2 * 3 + c1;   // absolute channel
                const int cw = c2 * 3 + c1;              // within-c3 index
                const float* trow = &tile[(c * 6 + pr) * 36 + ow0];
                float ra[3], rb[3];
#pragma unroll
                for (int kh = 0; kh < 3; ++kh) {
                    // taps ow0..ow0+3 (8B-aligned pairs)
                    const float2 u0 = *(const float2*)(trow + kh * 36);
                    const float2 u1 = *(const float2*)(trow + kh * 36 + 2);
                    const float w0 = wp[cw * 9 + kh * 3 + 0];
                    const float w1 = wp[cw * 9 + kh * 3 + 1];
                    const float w2 = wp[cw * 9 + kh * 3 + 2];
                    // leaf: s = (x*w+1)/2 = (0.5x)*w + 0.5; level 1: kw
                    ra[kh] = maj3(fmaf(u0.x, w0, 0.5f), fmaf(u0.y, w1, 0.5f), fmaf(u1.x, w2, 0.5f));
                    rb[kh] = maj3(fmaf(u0.y, w0, 0.5f), fmaf(u1.x, w1, 0.5f), fmaf(u1.y, w2, 0.5f));
                }
                l3a[c1] = maj3(ra[0], ra[1], ra[2]);     // level 2: kh
                l3b[c1] = maj3(rb[0], rb[1], rb[2]);
            }
            l4a[c2] = maj3(l3a[0], l3a[1], l3a[2]);      // level 3: c1
            l4b[c2] = maj3(l3b[0], l3b[1], l3b[2]);
        }
        const float pa = maj3(l4a[0], l4a[1], l4a[2]);   // level 4: c2 (c3-partial)
        const float pb = maj3(l4b[0], l4b[1], l4b[2]);

        const int base = (oc_local * 128 + pr * 32 + ow0) * 3 + sub3;
        part[base]     = pa;
        part[base + 3] = pb;
    }
    __syncthreads();

    // ---- combine: level 5 over c3 + back-convert; 512 threads, 1 px each ----
    if (tid < 512) {
        const int ocl = tid >> 7;
        const int px  = tid & 127;
        const int oc2 = ocg * 4 + ocl;
        if (oc2 < OCC) {
            const int b0 = (ocl * 128 + px) * 3;
            const float y = fmaf(2.0f, maj3(part[b0], part[b0 + 1], part[b0 + 2]), -1.0f);
            const int oh = rg * 4 + (px >> 5);
            const int ow = px & 31;
            out[(((n * OCC + oc2) * HH) + oh) * WW + ow] = y;
        }
    }
}

extern "C" void kernel_launch(void* const* d_in, const int* in_sizes, int n_in,
                              void* d_out, int out_size, void* d_ws, size_t ws_size,
                              hipStream_t stream) {
    const float* x = (const float*)d_in[0];
    const float* w = (const float*)d_in[1];
    float* out = (float*)d_out;
    // grid: 8 n * 7 oc-groups * 8 row-groups = 448 blocks, 768 threads (12 waves)
    sconv_maj_kernel<<<dim3(8 * 7 * 8), dim3(768), 0, stream>>>(x, w, out);
}